// Round 1
// baseline (798.520 us; speedup 1.0000x reference)
//
#include <hip/hip_runtime.h>

#define IN_F 128
#define HID 64
#define NCLS 4
#define BN_EPS 1e-5f

// ---------------- CSR build ----------------

__global__ void k_init(int* __restrict__ degi, float* __restrict__ stats, int n) {
    int i = blockIdx.x * blockDim.x + threadIdx.x;
    if (i < n) degi[i] = 0;
    if (i < 256) stats[i] = 0.f;
}

__global__ void k_count(const int* __restrict__ dst, int* __restrict__ degi, int e) {
    int i = blockIdx.x * blockDim.x + threadIdx.x;
    if (i < e) atomicAdd(&degi[dst[i]], 1);
}

__global__ __launch_bounds__(1024) void k_scan(const int* __restrict__ degi,
                                               int* __restrict__ rowptr,
                                               int* __restrict__ cursor,
                                               float* __restrict__ dinv,
                                               int n, int e) {
    __shared__ int part[1025];
    int t = threadIdx.x;
    int chunk = (n + 1023) >> 10;
    int b0 = t * chunk;
    int b1 = b0 + chunk; if (b1 > n) b1 = n;
    int s = 0;
    for (int i = b0; i < b1; ++i) s += degi[i];
    part[t] = s;
    __syncthreads();
    if (t == 0) {
        int run = 0;
        for (int i = 0; i < 1024; ++i) { int v = part[i]; part[i] = run; run += v; }
        part[1024] = run;
    }
    __syncthreads();
    int run = part[t];
    for (int i = b0; i < b1; ++i) {
        int c = degi[i];
        rowptr[i] = run;
        cursor[i] = run;
        dinv[i] = 1.0f / sqrtf((float)(c + 1));   // deg includes self-loop
        run += c;
    }
    if (t == 0) rowptr[n] = e;
}

__global__ void k_fill(const int* __restrict__ src, const int* __restrict__ dst,
                       int* __restrict__ cursor, int* __restrict__ csr, int e) {
    int i = blockIdx.x * blockDim.x + threadIdx.x;
    if (i < e) {
        int pos = atomicAdd(&cursor[dst[i]], 1);
        csr[pos] = src[i];
    }
}

// ---------------- GEMMs (thread-per-row, W in LDS) ----------------

// hs[r,:] = (x[r,:] @ W1) * dinv[r]      x:[n,128] W1:[128,64]
__global__ __launch_bounds__(256) void k_gemm1(const float* __restrict__ x,
                                               const float* __restrict__ W,
                                               const float* __restrict__ dinv,
                                               float* __restrict__ hs, int n) {
    __shared__ float4 Ws[IN_F * HID / 4];   // 2048 float4 = 32 KB
    int t = threadIdx.x;
    const float4* W4 = (const float4*)W;
#pragma unroll
    for (int i = 0; i < 8; ++i) Ws[t + i * 256] = W4[t + i * 256];
    __syncthreads();
    int r = blockIdx.x * 256 + t;
    if (r >= n) return;
    float4 acc[16];
#pragma unroll
    for (int j = 0; j < 16; ++j) acc[j] = make_float4(0.f, 0.f, 0.f, 0.f);
    const float4* xr = (const float4*)(x + (size_t)r * IN_F);
    for (int kk = 0; kk < 32; ++kk) {
        float4 xv = xr[kk];
#pragma unroll
        for (int l = 0; l < 4; ++l) {
            float xs = (l == 0) ? xv.x : (l == 1) ? xv.y : (l == 2) ? xv.z : xv.w;
            const float4* wr = &Ws[(kk * 4 + l) * 16];
#pragma unroll
            for (int j = 0; j < 16; ++j) {
                float4 w = wr[j];
                acc[j].x += xs * w.x; acc[j].y += xs * w.y;
                acc[j].z += xs * w.z; acc[j].w += xs * w.w;
            }
        }
    }
    float dv = dinv[r];
    float4* out = (float4*)(hs + (size_t)r * HID);
#pragma unroll
    for (int j = 0; j < 16; ++j)
        out[j] = make_float4(acc[j].x * dv, acc[j].y * dv, acc[j].z * dv, acc[j].w * dv);
}

// hs[r,:] = (relu(z[r,:]*sc+sh) @ W2) * dinv[r]    z:[n,64] W2:[64,64]
__global__ __launch_bounds__(256) void k_gemm2(const float* __restrict__ z,
                                               const float* __restrict__ W,
                                               const float* __restrict__ scsh,
                                               const float* __restrict__ dinv,
                                               float* __restrict__ hs, int n) {
    __shared__ float4 Ws[HID * HID / 4];    // 1024 float4 = 16 KB
    __shared__ float sc[64], sh[64];
    int t = threadIdx.x;
    const float4* W4 = (const float4*)W;
#pragma unroll
    for (int i = 0; i < 4; ++i) Ws[t + i * 256] = W4[t + i * 256];
    if (t < 64) { sc[t] = scsh[t]; sh[t] = scsh[64 + t]; }
    __syncthreads();
    int r = blockIdx.x * 256 + t;
    if (r >= n) return;
    float4 acc[16];
#pragma unroll
    for (int j = 0; j < 16; ++j) acc[j] = make_float4(0.f, 0.f, 0.f, 0.f);
    const float4* zr = (const float4*)(z + (size_t)r * HID);
    for (int kk = 0; kk < 16; ++kk) {
        float4 zv = zr[kk];
#pragma unroll
        for (int l = 0; l < 4; ++l) {
            int k = kk * 4 + l;
            float zs = (l == 0) ? zv.x : (l == 1) ? zv.y : (l == 2) ? zv.z : zv.w;
            float a = fmaxf(0.f, zs * sc[k] + sh[k]);
            const float4* wr = &Ws[k * 16];
#pragma unroll
            for (int j = 0; j < 16; ++j) {
                float4 w = wr[j];
                acc[j].x += a * w.x; acc[j].y += a * w.y;
                acc[j].z += a * w.z; acc[j].w += a * w.w;
            }
        }
    }
    float dv = dinv[r];
    float4* out = (float4*)(hs + (size_t)r * HID);
#pragma unroll
    for (int j = 0; j < 16; ++j)
        out[j] = make_float4(acc[j].x * dv, acc[j].y * dv, acc[j].z * dv, acc[j].w * dv);
}

// hs3[r,:] = (relu(z[r,:]*sc+sh) @ W3) * dinv[r]    z:[n,64] W3:[64,4]
__global__ __launch_bounds__(256) void k_gemm3(const float* __restrict__ z,
                                               const float* __restrict__ W,
                                               const float* __restrict__ scsh,
                                               const float* __restrict__ dinv,
                                               float* __restrict__ hs3, int n) {
    __shared__ float4 Ws[64];               // W3 64x4
    __shared__ float sc[64], sh[64];
    int t = threadIdx.x;
    if (t < 64) { Ws[t] = ((const float4*)W)[t]; sc[t] = scsh[t]; sh[t] = scsh[64 + t]; }
    __syncthreads();
    int r = blockIdx.x * 256 + t;
    if (r >= n) return;
    float4 acc = make_float4(0.f, 0.f, 0.f, 0.f);
    const float4* zr = (const float4*)(z + (size_t)r * HID);
    for (int kk = 0; kk < 16; ++kk) {
        float4 zv = zr[kk];
#pragma unroll
        for (int l = 0; l < 4; ++l) {
            int k = kk * 4 + l;
            float zs = (l == 0) ? zv.x : (l == 1) ? zv.y : (l == 2) ? zv.z : zv.w;
            float a = fmaxf(0.f, zs * sc[k] + sh[k]);
            float4 w = Ws[k];
            acc.x += a * w.x; acc.y += a * w.y; acc.z += a * w.z; acc.w += a * w.w;
        }
    }
    float dv = dinv[r];
    ((float4*)hs3)[r] = make_float4(acc.x * dv, acc.y * dv, acc.z * dv, acc.w * dv);
}

// ---------------- Aggregation (CSR gather) ----------------

// z[i,:] = dinv[i] * (hs[i,:] + sum_{s in nbr(i)} hs[s,:]) + bias
// plus per-channel sum / sumsq accumulation for BN.
__global__ __launch_bounds__(256) void k_agg64(const float* __restrict__ hs,
                                               const int* __restrict__ rowptr,
                                               const int* __restrict__ csr,
                                               const float* __restrict__ dinv,
                                               const float* __restrict__ bias,
                                               float* __restrict__ z,
                                               float* __restrict__ sums,
                                               float* __restrict__ sumsq, int n) {
    __shared__ float lsum[64], lsq[64];
    int t = threadIdx.x;
    if (t < 64) { lsum[t] = 0.f; lsq[t] = 0.f; }
    __syncthreads();
    const float4* h4 = (const float4*)hs;
    long long total = (long long)n * 16;
    int stride = gridDim.x * blockDim.x;      // multiple of 16 -> c4 invariant
    int gid = blockIdx.x * blockDim.x + t;
    int c4 = gid & 15;
    float4 bv = ((const float4*)bias)[c4];
    float ps0 = 0.f, ps1 = 0.f, ps2 = 0.f, ps3 = 0.f;
    float pq0 = 0.f, pq1 = 0.f, pq2 = 0.f, pq3 = 0.f;
    for (long long w = gid; w < total; w += stride) {
        int i = (int)(w >> 4);
        float4 acc = h4[(size_t)i * 16 + c4];         // self-loop term
        int beg = rowptr[i], end = rowptr[i + 1];
        for (int j = beg; j < end; ++j) {
            int s = csr[j];
            float4 v = h4[(size_t)s * 16 + c4];
            acc.x += v.x; acc.y += v.y; acc.z += v.z; acc.w += v.w;
        }
        float dv = dinv[i];
        float4 zv = make_float4(acc.x * dv + bv.x, acc.y * dv + bv.y,
                                acc.z * dv + bv.z, acc.w * dv + bv.w);
        ((float4*)z)[(size_t)i * 16 + c4] = zv;
        ps0 += zv.x; ps1 += zv.y; ps2 += zv.z; ps3 += zv.w;
        pq0 += zv.x * zv.x; pq1 += zv.y * zv.y; pq2 += zv.z * zv.z; pq3 += zv.w * zv.w;
    }
    int cb = c4 * 4;
    atomicAdd(&lsum[cb + 0], ps0); atomicAdd(&lsum[cb + 1], ps1);
    atomicAdd(&lsum[cb + 2], ps2); atomicAdd(&lsum[cb + 3], ps3);
    atomicAdd(&lsq[cb + 0], pq0);  atomicAdd(&lsq[cb + 1], pq1);
    atomicAdd(&lsq[cb + 2], pq2);  atomicAdd(&lsq[cb + 3], pq3);
    __syncthreads();
    if (t < 64) { atomicAdd(&sums[t], lsum[t]); atomicAdd(&sumsq[t], lsq[t]); }
}

// out[i,:] = dinv[i] * (hs3[i,:] + sum_nbr hs3[s,:]) + b3
__global__ void k_agg4(const float* __restrict__ hs3, const int* __restrict__ rowptr,
                       const int* __restrict__ csr, const float* __restrict__ dinv,
                       const float* __restrict__ b3, float* __restrict__ out, int n) {
    int i = blockIdx.x * blockDim.x + threadIdx.x;
    if (i >= n) return;
    const float4* h4 = (const float4*)hs3;
    float4 acc = h4[i];
    int beg = rowptr[i], end = rowptr[i + 1];
    for (int j = beg; j < end; ++j) {
        float4 v = h4[csr[j]];
        acc.x += v.x; acc.y += v.y; acc.z += v.z; acc.w += v.w;
    }
    float dv = dinv[i];
    float4 bv = *(const float4*)b3;
    ((float4*)out)[i] = make_float4(acc.x * dv + bv.x, acc.y * dv + bv.y,
                                    acc.z * dv + bv.z, acc.w * dv + bv.w);
}

__global__ void k_bnstats(const float* __restrict__ sums, const float* __restrict__ sumsq,
                          const float* __restrict__ g, const float* __restrict__ be,
                          float* __restrict__ scsh, int n) {
    int t = threadIdx.x;
    if (t < 64) {
        float inv_n = 1.f / (float)n;
        float m = sums[t] * inv_n;
        float v = sumsq[t] * inv_n - m * m;
        float sc = g[t] / sqrtf(v + BN_EPS);
        scsh[t] = sc;
        scsh[64 + t] = be[t] - m * sc;
    }
}

// ---------------- launch ----------------

extern "C" void kernel_launch(void* const* d_in, const int* in_sizes, int n_in,
                              void* d_out, int out_size, void* d_ws, size_t ws_size,
                              hipStream_t stream) {
    const float* x   = (const float*)d_in[0];
    const int*   ei  = (const int*)d_in[1];
    const float* W1  = (const float*)d_in[2];
    const float* b1  = (const float*)d_in[3];
    const float* g1  = (const float*)d_in[4];
    const float* be1 = (const float*)d_in[5];
    const float* W2  = (const float*)d_in[6];
    const float* b2  = (const float*)d_in[7];
    const float* g2  = (const float*)d_in[8];
    const float* be2 = (const float*)d_in[9];
    const float* W3  = (const float*)d_in[10];
    const float* b3  = (const float*)d_in[11];

    int n = in_sizes[0] / IN_F;
    int e = in_sizes[1] / 2;
    const int* src = ei;
    const int* dst = ei + e;

    float* wsf = (float*)d_ws;
    size_t NP = ((size_t)(n + 256) + 255) & ~(size_t)255;   // padded n (>= n+1)
    size_t EP = ((size_t)e + 255) & ~(size_t)255;
    size_t NB = (((size_t)n * HID) + 255) & ~(size_t)255;

    int*   degi   = (int*)wsf;
    float* dinv   = wsf + NP;
    int*   rowptr = (int*)(wsf + 2 * NP);
    int*   cursor = (int*)(wsf + 3 * NP);
    float* stats  = wsf + 4 * NP;          // 256: sums1,sumsq1,sums2,sumsq2
    float* scsh   = stats + 256;           // 256: sc1,sh1,sc2,sh2
    int*   csr    = (int*)(scsh + 256);
    float* A      = (float*)csr + EP;      // hs buffer [n,64]
    float* B      = A + NB;                // z  buffer [n,64]
    float* hs3    = B + NB;                // [n,4]

    int nb = (n + 255) / 256;
    int eb = (e + 255) / 256;

    k_init <<<nb, 256, 0, stream>>>(degi, stats, n);
    k_count<<<eb, 256, 0, stream>>>(dst, degi, e);
    k_scan <<<1, 1024, 0, stream>>>(degi, rowptr, cursor, dinv, n, e);
    k_fill <<<eb, 256, 0, stream>>>(src, dst, cursor, csr, e);

    // layer 1
    k_gemm1<<<nb, 256, 0, stream>>>(x, W1, dinv, A, n);
    k_agg64<<<1024, 256, 0, stream>>>(A, rowptr, csr, dinv, b1, B, stats, stats + 64, n);
    k_bnstats<<<1, 64, 0, stream>>>(stats, stats + 64, g1, be1, scsh, n);

    // layer 2
    k_gemm2<<<nb, 256, 0, stream>>>(B, W2, scsh, dinv, A, n);
    k_agg64<<<1024, 256, 0, stream>>>(A, rowptr, csr, dinv, b2, B, stats + 128, stats + 192, n);
    k_bnstats<<<1, 64, 0, stream>>>(stats + 128, stats + 192, g2, be2, scsh + 128, n);

    // layer 3
    k_gemm3<<<nb, 256, 0, stream>>>(B, W3, scsh + 128, dinv, hs3, n);
    k_agg4 <<<nb, 256, 0, stream>>>(hs3, rowptr, csr, dinv, b3, (float*)d_out, n);
}

// Round 2
// 531.153 us; speedup vs baseline: 1.5034x; 1.5034x over previous
//
#include <hip/hip_runtime.h>

#define IN_F 128
#define HID 64
#define NCLS 4
#define BN_EPS 1e-5f

// ---------------- CSR build ----------------

__global__ void k_init(int* __restrict__ degi, float* __restrict__ stats, int n) {
    int i = blockIdx.x * blockDim.x + threadIdx.x;
    if (i < n) degi[i] = 0;
    if (i < 256) stats[i] = 0.f;
}

__global__ void k_count(const int* __restrict__ dst, int* __restrict__ degi, int e) {
    int i = blockIdx.x * blockDim.x + threadIdx.x;
    if (i < e) atomicAdd(&degi[dst[i]], 1);
}

// ---- parallel exclusive scan of degi -> rowptr/cursor, plus dinv ----
// phase 1: per-block (1024 elems) reduce -> part[b]
__global__ __launch_bounds__(256) void k_scan1(const int* __restrict__ degi,
                                               int* __restrict__ part, int n) {
    int t = threadIdx.x;
    int base = blockIdx.x * 1024 + t * 4;
    int s = 0;
#pragma unroll
    for (int j = 0; j < 4; ++j) { int i = base + j; if (i < n) s += degi[i]; }
    __shared__ int red[256];
    red[t] = s; __syncthreads();
    for (int off = 128; off > 0; off >>= 1) {
        if (t < off) red[t] += red[t + off];
        __syncthreads();
    }
    if (t == 0) part[blockIdx.x] = red[0];
}

// phase 2: single-block exclusive scan of part[0..nb), nb <= 1024
__global__ __launch_bounds__(1024) void k_scan2(int* __restrict__ part, int nb) {
    __shared__ int sh[1024];
    int t = threadIdx.x;
    int v = (t < nb) ? part[t] : 0;
    sh[t] = v; __syncthreads();
    for (int off = 1; off < 1024; off <<= 1) {
        int add = (t >= off) ? sh[t - off] : 0;
        __syncthreads();
        sh[t] += add;
        __syncthreads();
    }
    if (t < nb) part[t] = sh[t] - v;   // exclusive
}

// phase 3: per-block apply — in-block scan + global offset, write rowptr/cursor/dinv
__global__ __launch_bounds__(256) void k_scan3(const int* __restrict__ degi,
                                               const int* __restrict__ part,
                                               int* __restrict__ rowptr,
                                               int* __restrict__ cursor,
                                               float* __restrict__ dinv,
                                               int n, int e) {
    int t = threadIdx.x;
    int base = blockIdx.x * 1024 + t * 4;
    int d[4]; int s = 0;
#pragma unroll
    for (int j = 0; j < 4; ++j) { int i = base + j; d[j] = (i < n) ? degi[i] : 0; s += d[j]; }
    __shared__ int sh[256];
    sh[t] = s; __syncthreads();
    for (int off = 1; off < 256; off <<= 1) {
        int add = (t >= off) ? sh[t - off] : 0;
        __syncthreads();
        sh[t] += add;
        __syncthreads();
    }
    int run = part[blockIdx.x] + sh[t] - s;   // exclusive offset for this thread
#pragma unroll
    for (int j = 0; j < 4; ++j) {
        int i = base + j;
        if (i < n) {
            rowptr[i] = run;
            cursor[i] = run;
            dinv[i] = 1.0f / sqrtf((float)(d[j] + 1));   // deg includes self-loop
            run += d[j];
        }
    }
    if (blockIdx.x == 0 && t == 0) rowptr[n] = e;
}

__global__ void k_fill(const int* __restrict__ src, const int* __restrict__ dst,
                       int* __restrict__ cursor, int* __restrict__ csr, int e) {
    int i = blockIdx.x * blockDim.x + threadIdx.x;
    if (i < e) {
        int pos = atomicAdd(&cursor[dst[i]], 1);
        csr[pos] = src[i];
    }
}

// ---------------- GEMMs (thread-per-row, W in LDS) ----------------

// hs[r,:] = (x[r,:] @ W1) * dinv[r]      x:[n,128] W1:[128,64]
__global__ __launch_bounds__(256) void k_gemm1(const float* __restrict__ x,
                                               const float* __restrict__ W,
                                               const float* __restrict__ dinv,
                                               float* __restrict__ hs, int n) {
    __shared__ float4 Ws[IN_F * HID / 4];   // 2048 float4 = 32 KB
    int t = threadIdx.x;
    const float4* W4 = (const float4*)W;
#pragma unroll
    for (int i = 0; i < 8; ++i) Ws[t + i * 256] = W4[t + i * 256];
    __syncthreads();
    int r = blockIdx.x * 256 + t;
    if (r >= n) return;
    float4 acc[16];
#pragma unroll
    for (int j = 0; j < 16; ++j) acc[j] = make_float4(0.f, 0.f, 0.f, 0.f);
    const float4* xr = (const float4*)(x + (size_t)r * IN_F);
    for (int kk = 0; kk < 32; ++kk) {
        float4 xv = xr[kk];
#pragma unroll
        for (int l = 0; l < 4; ++l) {
            float xs = (l == 0) ? xv.x : (l == 1) ? xv.y : (l == 2) ? xv.z : xv.w;
            const float4* wr = &Ws[(kk * 4 + l) * 16];
#pragma unroll
            for (int j = 0; j < 16; ++j) {
                float4 w = wr[j];
                acc[j].x += xs * w.x; acc[j].y += xs * w.y;
                acc[j].z += xs * w.z; acc[j].w += xs * w.w;
            }
        }
    }
    float dv = dinv[r];
    float4* out = (float4*)(hs + (size_t)r * HID);
#pragma unroll
    for (int j = 0; j < 16; ++j)
        out[j] = make_float4(acc[j].x * dv, acc[j].y * dv, acc[j].z * dv, acc[j].w * dv);
}

// hs[r,:] = (relu(z[r,:]*sc+sh) @ W2) * dinv[r]    z:[n,64] W2:[64,64]
__global__ __launch_bounds__(256) void k_gemm2(const float* __restrict__ z,
                                               const float* __restrict__ W,
                                               const float* __restrict__ scsh,
                                               const float* __restrict__ dinv,
                                               float* __restrict__ hs, int n) {
    __shared__ float4 Ws[HID * HID / 4];    // 1024 float4 = 16 KB
    __shared__ float sc[64], sh[64];
    int t = threadIdx.x;
    const float4* W4 = (const float4*)W;
#pragma unroll
    for (int i = 0; i < 4; ++i) Ws[t + i * 256] = W4[t + i * 256];
    if (t < 64) { sc[t] = scsh[t]; sh[t] = scsh[64 + t]; }
    __syncthreads();
    int r = blockIdx.x * 256 + t;
    if (r >= n) return;
    float4 acc[16];
#pragma unroll
    for (int j = 0; j < 16; ++j) acc[j] = make_float4(0.f, 0.f, 0.f, 0.f);
    const float4* zr = (const float4*)(z + (size_t)r * HID);
    for (int kk = 0; kk < 16; ++kk) {
        float4 zv = zr[kk];
#pragma unroll
        for (int l = 0; l < 4; ++l) {
            int k = kk * 4 + l;
            float zs = (l == 0) ? zv.x : (l == 1) ? zv.y : (l == 2) ? zv.z : zv.w;
            float a = fmaxf(0.f, zs * sc[k] + sh[k]);
            const float4* wr = &Ws[k * 16];
#pragma unroll
            for (int j = 0; j < 16; ++j) {
                float4 w = wr[j];
                acc[j].x += a * w.x; acc[j].y += a * w.y;
                acc[j].z += a * w.z; acc[j].w += a * w.w;
            }
        }
    }
    float dv = dinv[r];
    float4* out = (float4*)(hs + (size_t)r * HID);
#pragma unroll
    for (int j = 0; j < 16; ++j)
        out[j] = make_float4(acc[j].x * dv, acc[j].y * dv, acc[j].z * dv, acc[j].w * dv);
}

// hs3[r,:] = (relu(z[r,:]*sc+sh) @ W3) * dinv[r]    z:[n,64] W3:[64,4]
__global__ __launch_bounds__(256) void k_gemm3(const float* __restrict__ z,
                                               const float* __restrict__ W,
                                               const float* __restrict__ scsh,
                                               const float* __restrict__ dinv,
                                               float* __restrict__ hs3, int n) {
    __shared__ float4 Ws[64];               // W3 64x4
    __shared__ float sc[64], sh[64];
    int t = threadIdx.x;
    if (t < 64) { Ws[t] = ((const float4*)W)[t]; sc[t] = scsh[t]; sh[t] = scsh[64 + t]; }
    __syncthreads();
    int r = blockIdx.x * 256 + t;
    if (r >= n) return;
    float4 acc = make_float4(0.f, 0.f, 0.f, 0.f);
    const float4* zr = (const float4*)(z + (size_t)r * HID);
    for (int kk = 0; kk < 16; ++kk) {
        float4 zv = zr[kk];
#pragma unroll
        for (int l = 0; l < 4; ++l) {
            int k = kk * 4 + l;
            float zs = (l == 0) ? zv.x : (l == 1) ? zv.y : (l == 2) ? zv.z : zv.w;
            float a = fmaxf(0.f, zs * sc[k] + sh[k]);
            float4 w = Ws[k];
            acc.x += a * w.x; acc.y += a * w.y; acc.z += a * w.z; acc.w += a * w.w;
        }
    }
    float dv = dinv[r];
    ((float4*)hs3)[r] = make_float4(acc.x * dv, acc.y * dv, acc.z * dv, acc.w * dv);
}

// ---------------- Aggregation (CSR gather) ----------------

// z[i,:] = dinv[i] * (hs[i,:] + sum_{s in nbr(i)} hs[s,:]) + bias
// plus per-channel sum / sumsq accumulation for BN.
__global__ __launch_bounds__(256) void k_agg64(const float* __restrict__ hs,
                                               const int* __restrict__ rowptr,
                                               const int* __restrict__ csr,
                                               const float* __restrict__ dinv,
                                               const float* __restrict__ bias,
                                               float* __restrict__ z,
                                               float* __restrict__ sums,
                                               float* __restrict__ sumsq, int n) {
    __shared__ float lsum[64], lsq[64];
    int t = threadIdx.x;
    if (t < 64) { lsum[t] = 0.f; lsq[t] = 0.f; }
    __syncthreads();
    const float4* h4 = (const float4*)hs;
    long long total = (long long)n * 16;
    int stride = gridDim.x * blockDim.x;      // multiple of 16 -> c4 invariant
    int gid = blockIdx.x * blockDim.x + t;
    int c4 = gid & 15;
    float4 bv = ((const float4*)bias)[c4];
    float ps0 = 0.f, ps1 = 0.f, ps2 = 0.f, ps3 = 0.f;
    float pq0 = 0.f, pq1 = 0.f, pq2 = 0.f, pq3 = 0.f;
    for (long long w = gid; w < total; w += stride) {
        int i = (int)(w >> 4);
        float4 acc = h4[(size_t)i * 16 + c4];         // self-loop term
        int beg = rowptr[i], end = rowptr[i + 1];
        for (int j = beg; j < end; ++j) {
            int s = csr[j];
            float4 v = h4[(size_t)s * 16 + c4];
            acc.x += v.x; acc.y += v.y; acc.z += v.z; acc.w += v.w;
        }
        float dv = dinv[i];
        float4 zv = make_float4(acc.x * dv + bv.x, acc.y * dv + bv.y,
                                acc.z * dv + bv.z, acc.w * dv + bv.w);
        ((float4*)z)[(size_t)i * 16 + c4] = zv;
        ps0 += zv.x; ps1 += zv.y; ps2 += zv.z; ps3 += zv.w;
        pq0 += zv.x * zv.x; pq1 += zv.y * zv.y; pq2 += zv.z * zv.z; pq3 += zv.w * zv.w;
    }
    int cb = c4 * 4;
    atomicAdd(&lsum[cb + 0], ps0); atomicAdd(&lsum[cb + 1], ps1);
    atomicAdd(&lsum[cb + 2], ps2); atomicAdd(&lsum[cb + 3], ps3);
    atomicAdd(&lsq[cb + 0], pq0);  atomicAdd(&lsq[cb + 1], pq1);
    atomicAdd(&lsq[cb + 2], pq2);  atomicAdd(&lsq[cb + 3], pq3);
    __syncthreads();
    if (t < 64) { atomicAdd(&sums[t], lsum[t]); atomicAdd(&sumsq[t], lsq[t]); }
}

// out[i,:] = dinv[i] * (hs3[i,:] + sum_nbr hs3[s,:]) + b3
__global__ void k_agg4(const float* __restrict__ hs3, const int* __restrict__ rowptr,
                       const int* __restrict__ csr, const float* __restrict__ dinv,
                       const float* __restrict__ b3, float* __restrict__ out, int n) {
    int i = blockIdx.x * blockDim.x + threadIdx.x;
    if (i >= n) return;
    const float4* h4 = (const float4*)hs3;
    float4 acc = h4[i];
    int beg = rowptr[i], end = rowptr[i + 1];
    for (int j = beg; j < end; ++j) {
        float4 v = h4[csr[j]];
        acc.x += v.x; acc.y += v.y; acc.z += v.z; acc.w += v.w;
    }
    float dv = dinv[i];
    float4 bv = *(const float4*)b3;
    ((float4*)out)[i] = make_float4(acc.x * dv + bv.x, acc.y * dv + bv.y,
                                    acc.z * dv + bv.z, acc.w * dv + bv.w);
}

__global__ void k_bnstats(const float* __restrict__ sums, const float* __restrict__ sumsq,
                          const float* __restrict__ g, const float* __restrict__ be,
                          float* __restrict__ scsh, int n) {
    int t = threadIdx.x;
    if (t < 64) {
        float inv_n = 1.f / (float)n;
        float m = sums[t] * inv_n;
        float v = sumsq[t] * inv_n - m * m;
        float sc = g[t] / sqrtf(v + BN_EPS);
        scsh[t] = sc;
        scsh[64 + t] = be[t] - m * sc;
    }
}

// ---------------- launch ----------------

extern "C" void kernel_launch(void* const* d_in, const int* in_sizes, int n_in,
                              void* d_out, int out_size, void* d_ws, size_t ws_size,
                              hipStream_t stream) {
    const float* x   = (const float*)d_in[0];
    const int*   ei  = (const int*)d_in[1];
    const float* W1  = (const float*)d_in[2];
    const float* b1  = (const float*)d_in[3];
    const float* g1  = (const float*)d_in[4];
    const float* be1 = (const float*)d_in[5];
    const float* W2  = (const float*)d_in[6];
    const float* b2  = (const float*)d_in[7];
    const float* g2  = (const float*)d_in[8];
    const float* be2 = (const float*)d_in[9];
    const float* W3  = (const float*)d_in[10];
    const float* b3  = (const float*)d_in[11];

    int n = in_sizes[0] / IN_F;
    int e = in_sizes[1] / 2;
    const int* src = ei;
    const int* dst = ei + e;

    float* wsf = (float*)d_ws;
    size_t NP = ((size_t)(n + 256) + 255) & ~(size_t)255;   // padded n (>= n+1)
    size_t EP = ((size_t)e + 255) & ~(size_t)255;
    size_t NB = (((size_t)n * HID) + 255) & ~(size_t)255;

    int*   degi   = (int*)wsf;
    float* dinv   = wsf + NP;
    int*   rowptr = (int*)(wsf + 2 * NP);
    int*   cursor = (int*)(wsf + 3 * NP);
    float* stats  = wsf + 4 * NP;          // 256: sums1,sumsq1,sums2,sumsq2
    float* scsh   = stats + 256;           // 256: sc1,sh1,sc2,sh2
    int*   part   = (int*)(scsh + 256);    // 1024: scan partials
    int*   csr    = (int*)part + 1024;
    float* A      = (float*)csr + EP;      // hs buffer [n,64]
    float* B      = A + NB;                // z  buffer [n,64]
    float* hs3    = B + NB;                // [n,4]

    int nb = (n + 255) / 256;
    int eb = (e + 255) / 256;
    int sb = (n + 1023) / 1024;            // scan blocks (<= 1024)

    k_init <<<nb, 256, 0, stream>>>(degi, stats, n);
    k_count<<<eb, 256, 0, stream>>>(dst, degi, e);
    k_scan1<<<sb, 256, 0, stream>>>(degi, part, n);
    k_scan2<<<1, 1024, 0, stream>>>(part, sb);
    k_scan3<<<sb, 256, 0, stream>>>(degi, part, rowptr, cursor, dinv, n, e);
    k_fill <<<eb, 256, 0, stream>>>(src, dst, cursor, csr, e);

    // layer 1
    k_gemm1<<<nb, 256, 0, stream>>>(x, W1, dinv, A, n);
    k_agg64<<<1024, 256, 0, stream>>>(A, rowptr, csr, dinv, b1, B, stats, stats + 64, n);
    k_bnstats<<<1, 64, 0, stream>>>(stats, stats + 64, g1, be1, scsh, n);

    // layer 2
    k_gemm2<<<nb, 256, 0, stream>>>(B, W2, scsh, dinv, A, n);
    k_agg64<<<1024, 256, 0, stream>>>(A, rowptr, csr, dinv, b2, B, stats + 128, stats + 192, n);
    k_bnstats<<<1, 64, 0, stream>>>(stats + 128, stats + 192, g2, be2, scsh + 128, n);

    // layer 3
    k_gemm3<<<nb, 256, 0, stream>>>(B, W3, scsh + 128, dinv, hs3, n);
    k_agg4 <<<nb, 256, 0, stream>>>(hs3, rowptr, csr, dinv, b3, (float*)d_out, n);
}

// Round 3
// 487.107 us; speedup vs baseline: 1.6393x; 1.0904x over previous
//
#include <hip/hip_runtime.h>

#define IN_F 128
#define HID 64
#define NCLS 4
#define BN_EPS 1e-5f

#define MAXB 512        // max buckets (n <= 131072)
#define BSH 8           // bucket = dst >> 8  (256 nodes per bucket)
#define CHUNK 4096      // edges per block in chunked passes

// ---------------- CSR build ----------------

__global__ void k_init(int* __restrict__ degi, float* __restrict__ stats,
                       int* __restrict__ bhist, int n) {
    int i = blockIdx.x * blockDim.x + threadIdx.x;
    if (i < n) degi[i] = 0;
    if (i < 256) stats[i] = 0.f;
    if (i < MAXB) bhist[i] = 0;
}

// per-node degree + per-bucket histogram (chunked, LDS-staged flush)
__global__ __launch_bounds__(256) void k_count(const int* __restrict__ dst,
                                               int* __restrict__ degi,
                                               int* __restrict__ bhist, int e) {
    __shared__ int lh[MAXB];
    int t = threadIdx.x;
    for (int i = t; i < MAXB; i += 256) lh[i] = 0;
    __syncthreads();
    int base = blockIdx.x * CHUNK;
    int m = min(CHUNK, e - base);
    for (int i = t; i < m; i += 256) {
        int d = dst[base + i];
        atomicAdd(&degi[d], 1);
        atomicAdd(&lh[d >> BSH], 1);
    }
    __syncthreads();
    for (int b = t; b < MAXB; b += 256) { int c = lh[b]; if (c) atomicAdd(&bhist[b], c); }
}

// ---- parallel exclusive scan of degi -> rowptr/cursor, plus dinv ----
__global__ __launch_bounds__(256) void k_scan1(const int* __restrict__ degi,
                                               int* __restrict__ part, int n) {
    int t = threadIdx.x;
    int base = blockIdx.x * 1024 + t * 4;
    int s = 0;
#pragma unroll
    for (int j = 0; j < 4; ++j) { int i = base + j; if (i < n) s += degi[i]; }
    __shared__ int red[256];
    red[t] = s; __syncthreads();
    for (int off = 128; off > 0; off >>= 1) {
        if (t < off) red[t] += red[t + off];
        __syncthreads();
    }
    if (t == 0) part[blockIdx.x] = red[0];
}

__global__ __launch_bounds__(1024) void k_scan2(int* __restrict__ part, int nb) {
    __shared__ int sh[1024];
    int t = threadIdx.x;
    int v = (t < nb) ? part[t] : 0;
    sh[t] = v; __syncthreads();
    for (int off = 1; off < 1024; off <<= 1) {
        int add = (t >= off) ? sh[t - off] : 0;
        __syncthreads();
        sh[t] += add;
        __syncthreads();
    }
    if (t < nb) part[t] = sh[t] - v;   // exclusive
}

__global__ __launch_bounds__(256) void k_scan3(const int* __restrict__ degi,
                                               const int* __restrict__ part,
                                               int* __restrict__ rowptr,
                                               int* __restrict__ cursor,
                                               float* __restrict__ dinv,
                                               int n, int e) {
    int t = threadIdx.x;
    int base = blockIdx.x * 1024 + t * 4;
    int d[4]; int s = 0;
#pragma unroll
    for (int j = 0; j < 4; ++j) { int i = base + j; d[j] = (i < n) ? degi[i] : 0; s += d[j]; }
    __shared__ int sh[256];
    sh[t] = s; __syncthreads();
    for (int off = 1; off < 256; off <<= 1) {
        int add = (t >= off) ? sh[t - off] : 0;
        __syncthreads();
        sh[t] += add;
        __syncthreads();
    }
    int run = part[blockIdx.x] + sh[t] - s;
#pragma unroll
    for (int j = 0; j < 4; ++j) {
        int i = base + j;
        if (i < n) {
            rowptr[i] = run;
            cursor[i] = run;
            dinv[i] = 1.0f / sqrtf((float)(d[j] + 1));   // deg includes self-loop
            run += d[j];
        }
    }
    if (blockIdx.x == 0 && t == 0) rowptr[n] = e;
}

// exclusive scan of bucket histogram -> boff, bcur
__global__ __launch_bounds__(512) void k_bscan(const int* __restrict__ bhist,
                                               int* __restrict__ boff,
                                               int* __restrict__ bcur,
                                               int nbkt, int e) {
    __shared__ int sh[512];
    int t = threadIdx.x;
    int v = (t < nbkt) ? bhist[t] : 0;
    sh[t] = v; __syncthreads();
    for (int off = 1; off < 512; off <<= 1) {
        int add = (t >= off) ? sh[t - off] : 0;
        __syncthreads();
        sh[t] += add;
        __syncthreads();
    }
    if (t < nbkt) { int ex = sh[t] - v; boff[t] = ex; bcur[t] = ex; }
    if (t == 0) boff[nbkt] = e;
}

// phase A: bin (src,dst) pairs by dst-bucket with LDS multisplit, coalesced writes
__global__ __launch_bounds__(256) void k_bin(const int* __restrict__ src,
                                             const int* __restrict__ dst,
                                             int* __restrict__ bcur,
                                             uint2* __restrict__ pairs, int e) {
    __shared__ uint2 stage[CHUNK];
    __shared__ int cnt[MAXB], off[MAXB], gbase[MAXB];
    int t = threadIdx.x;
    for (int i = t; i < MAXB; i += 256) cnt[i] = 0;
    __syncthreads();
    int base = blockIdx.x * CHUNK;
    int m = min(CHUNK, e - base);
    int lr[CHUNK / 256];
#pragma unroll
    for (int j = 0; j < CHUNK / 256; ++j) {
        int i = t + j * 256;
        if (i < m) lr[j] = atomicAdd(&cnt[dst[base + i] >> BSH], 1);
    }
    __syncthreads();
    // inclusive scan of cnt (512 entries, 256 threads, Hillis-Steele, 2/thread)
    off[t] = cnt[t]; off[t + 256] = cnt[t + 256];
    __syncthreads();
    for (int o = 1; o < 512; o <<= 1) {
        int v0 = (t >= o) ? off[t - o] : 0;
        int v1 = (t + 256 >= o) ? off[t + 256 - o] : 0;
        __syncthreads();
        off[t] += v0; off[t + 256] += v1;
        __syncthreads();
    }
    // reserve global range; bias so global addr = gbase[b] + stage_index
    for (int b = t; b < MAXB; b += 256) {
        int c = cnt[b];
        int ex = off[b] - c;                       // exclusive local offset
        gbase[b] = c ? (atomicAdd(&bcur[b], c) - ex) : 0;
    }
    __syncthreads();
#pragma unroll
    for (int j = 0; j < CHUNK / 256; ++j) {
        int i = t + j * 256;
        if (i < m) {
            int s = src[base + i], d = dst[base + i];
            int b = d >> BSH;
            stage[(off[b] - cnt[b]) + lr[j]] = make_uint2((unsigned)s, (unsigned)d);
        }
    }
    __syncthreads();
    for (int i = t; i < m; i += 256) {
        uint2 p = stage[i];
        int b = (int)(p.y >> BSH);
        pairs[gbase[b] + i] = p;
    }
}

// phase B: per-bucket scatter into csr (scatter span ~16KB -> stays in L2)
__global__ __launch_bounds__(256) void k_fill2(const uint2* __restrict__ pairs,
                                               const int* __restrict__ boff,
                                               int* __restrict__ cursor,
                                               int* __restrict__ csr) {
    int b = blockIdx.x;
    int beg = boff[b], end = boff[b + 1];
    for (int i = beg + threadIdx.x; i < end; i += 256) {
        uint2 p = pairs[i];
        int pos = atomicAdd(&cursor[p.y], 1);
        csr[pos] = (int)p.x;
    }
}

// ---------------- GEMMs (thread-per-row, W in LDS) ----------------

__global__ __launch_bounds__(256) void k_gemm1(const float* __restrict__ x,
                                               const float* __restrict__ W,
                                               const float* __restrict__ dinv,
                                               float* __restrict__ hs, int n) {
    __shared__ float4 Ws[IN_F * HID / 4];   // 32 KB
    int t = threadIdx.x;
    const float4* W4 = (const float4*)W;
#pragma unroll
    for (int i = 0; i < 8; ++i) Ws[t + i * 256] = W4[t + i * 256];
    __syncthreads();
    int r = blockIdx.x * 256 + t;
    if (r >= n) return;
    float4 acc[16];
#pragma unroll
    for (int j = 0; j < 16; ++j) acc[j] = make_float4(0.f, 0.f, 0.f, 0.f);
    const float4* xr = (const float4*)(x + (size_t)r * IN_F);
    for (int kk = 0; kk < 32; ++kk) {
        float4 xv = xr[kk];
#pragma unroll
        for (int l = 0; l < 4; ++l) {
            float xs = (l == 0) ? xv.x : (l == 1) ? xv.y : (l == 2) ? xv.z : xv.w;
            const float4* wr = &Ws[(kk * 4 + l) * 16];
#pragma unroll
            for (int j = 0; j < 16; ++j) {
                float4 w = wr[j];
                acc[j].x += xs * w.x; acc[j].y += xs * w.y;
                acc[j].z += xs * w.z; acc[j].w += xs * w.w;
            }
        }
    }
    float dv = dinv[r];
    float4* out = (float4*)(hs + (size_t)r * HID);
#pragma unroll
    for (int j = 0; j < 16; ++j)
        out[j] = make_float4(acc[j].x * dv, acc[j].y * dv, acc[j].z * dv, acc[j].w * dv);
}

__global__ __launch_bounds__(256) void k_gemm2(const float* __restrict__ z,
                                               const float* __restrict__ W,
                                               const float* __restrict__ scsh,
                                               const float* __restrict__ dinv,
                                               float* __restrict__ hs, int n) {
    __shared__ float4 Ws[HID * HID / 4];    // 16 KB
    __shared__ float sc[64], sh[64];
    int t = threadIdx.x;
    const float4* W4 = (const float4*)W;
#pragma unroll
    for (int i = 0; i < 4; ++i) Ws[t + i * 256] = W4[t + i * 256];
    if (t < 64) { sc[t] = scsh[t]; sh[t] = scsh[64 + t]; }
    __syncthreads();
    int r = blockIdx.x * 256 + t;
    if (r >= n) return;
    float4 acc[16];
#pragma unroll
    for (int j = 0; j < 16; ++j) acc[j] = make_float4(0.f, 0.f, 0.f, 0.f);
    const float4* zr = (const float4*)(z + (size_t)r * HID);
    for (int kk = 0; kk < 16; ++kk) {
        float4 zv = zr[kk];
#pragma unroll
        for (int l = 0; l < 4; ++l) {
            int k = kk * 4 + l;
            float zs = (l == 0) ? zv.x : (l == 1) ? zv.y : (l == 2) ? zv.z : zv.w;
            float a = fmaxf(0.f, zs * sc[k] + sh[k]);
            const float4* wr = &Ws[k * 16];
#pragma unroll
            for (int j = 0; j < 16; ++j) {
                float4 w = wr[j];
                acc[j].x += a * w.x; acc[j].y += a * w.y;
                acc[j].z += a * w.z; acc[j].w += a * w.w;
            }
        }
    }
    float dv = dinv[r];
    float4* out = (float4*)(hs + (size_t)r * HID);
#pragma unroll
    for (int j = 0; j < 16; ++j)
        out[j] = make_float4(acc[j].x * dv, acc[j].y * dv, acc[j].z * dv, acc[j].w * dv);
}

__global__ __launch_bounds__(256) void k_gemm3(const float* __restrict__ z,
                                               const float* __restrict__ W,
                                               const float* __restrict__ scsh,
                                               const float* __restrict__ dinv,
                                               float* __restrict__ hs3, int n) {
    __shared__ float4 Ws[64];
    __shared__ float sc[64], sh[64];
    int t = threadIdx.x;
    if (t < 64) { Ws[t] = ((const float4*)W)[t]; sc[t] = scsh[t]; sh[t] = scsh[64 + t]; }
    __syncthreads();
    int r = blockIdx.x * 256 + t;
    if (r >= n) return;
    float4 acc = make_float4(0.f, 0.f, 0.f, 0.f);
    const float4* zr = (const float4*)(z + (size_t)r * HID);
    for (int kk = 0; kk < 16; ++kk) {
        float4 zv = zr[kk];
#pragma unroll
        for (int l = 0; l < 4; ++l) {
            int k = kk * 4 + l;
            float zs = (l == 0) ? zv.x : (l == 1) ? zv.y : (l == 2) ? zv.z : zv.w;
            float a = fmaxf(0.f, zs * sc[k] + sh[k]);
            float4 w = Ws[k];
            acc.x += a * w.x; acc.y += a * w.y; acc.z += a * w.z; acc.w += a * w.w;
        }
    }
    float dv = dinv[r];
    ((float4*)hs3)[r] = make_float4(acc.x * dv, acc.y * dv, acc.z * dv, acc.w * dv);
}

// ---------------- Aggregation (CSR gather) ----------------

__global__ __launch_bounds__(256) void k_agg64(const float* __restrict__ hs,
                                               const int* __restrict__ rowptr,
                                               const int* __restrict__ csr,
                                               const float* __restrict__ dinv,
                                               const float* __restrict__ bias,
                                               float* __restrict__ z,
                                               float* __restrict__ sums,
                                               float* __restrict__ sumsq, int n) {
    __shared__ float lsum[64], lsq[64];
    int t = threadIdx.x;
    if (t < 64) { lsum[t] = 0.f; lsq[t] = 0.f; }
    __syncthreads();
    const float4* h4 = (const float4*)hs;
    long long total = (long long)n * 16;
    int stride = gridDim.x * blockDim.x;
    int gid = blockIdx.x * blockDim.x + t;
    int c4 = gid & 15;
    float4 bv = ((const float4*)bias)[c4];
    float ps0 = 0.f, ps1 = 0.f, ps2 = 0.f, ps3 = 0.f;
    float pq0 = 0.f, pq1 = 0.f, pq2 = 0.f, pq3 = 0.f;
    for (long long w = gid; w < total; w += stride) {
        int i = (int)(w >> 4);
        float4 acc = h4[(size_t)i * 16 + c4];
        int beg = rowptr[i], end = rowptr[i + 1];
        for (int j = beg; j < end; ++j) {
            int s = csr[j];
            float4 v = h4[(size_t)s * 16 + c4];
            acc.x += v.x; acc.y += v.y; acc.z += v.z; acc.w += v.w;
        }
        float dv = dinv[i];
        float4 zv = make_float4(acc.x * dv + bv.x, acc.y * dv + bv.y,
                                acc.z * dv + bv.z, acc.w * dv + bv.w);
        ((float4*)z)[(size_t)i * 16 + c4] = zv;
        ps0 += zv.x; ps1 += zv.y; ps2 += zv.z; ps3 += zv.w;
        pq0 += zv.x * zv.x; pq1 += zv.y * zv.y; pq2 += zv.z * zv.z; pq3 += zv.w * zv.w;
    }
    int cb = c4 * 4;
    atomicAdd(&lsum[cb + 0], ps0); atomicAdd(&lsum[cb + 1], ps1);
    atomicAdd(&lsum[cb + 2], ps2); atomicAdd(&lsum[cb + 3], ps3);
    atomicAdd(&lsq[cb + 0], pq0);  atomicAdd(&lsq[cb + 1], pq1);
    atomicAdd(&lsq[cb + 2], pq2);  atomicAdd(&lsq[cb + 3], pq3);
    __syncthreads();
    if (t < 64) { atomicAdd(&sums[t], lsum[t]); atomicAdd(&sumsq[t], lsq[t]); }
}

__global__ void k_agg4(const float* __restrict__ hs3, const int* __restrict__ rowptr,
                       const int* __restrict__ csr, const float* __restrict__ dinv,
                       const float* __restrict__ b3, float* __restrict__ out, int n) {
    int i = blockIdx.x * blockDim.x + threadIdx.x;
    if (i >= n) return;
    const float4* h4 = (const float4*)hs3;
    float4 acc = h4[i];
    int beg = rowptr[i], end = rowptr[i + 1];
    for (int j = beg; j < end; ++j) {
        float4 v = h4[csr[j]];
        acc.x += v.x; acc.y += v.y; acc.z += v.z; acc.w += v.w;
    }
    float dv = dinv[i];
    float4 bv = *(const float4*)b3;
    ((float4*)out)[i] = make_float4(acc.x * dv + bv.x, acc.y * dv + bv.y,
                                    acc.z * dv + bv.z, acc.w * dv + bv.w);
}

__global__ void k_bnstats(const float* __restrict__ sums, const float* __restrict__ sumsq,
                          const float* __restrict__ g, const float* __restrict__ be,
                          float* __restrict__ scsh, int n) {
    int t = threadIdx.x;
    if (t < 64) {
        float inv_n = 1.f / (float)n;
        float m = sums[t] * inv_n;
        float v = sumsq[t] * inv_n - m * m;
        float sc = g[t] / sqrtf(v + BN_EPS);
        scsh[t] = sc;
        scsh[64 + t] = be[t] - m * sc;
    }
}

// ---------------- launch ----------------

extern "C" void kernel_launch(void* const* d_in, const int* in_sizes, int n_in,
                              void* d_out, int out_size, void* d_ws, size_t ws_size,
                              hipStream_t stream) {
    const float* x   = (const float*)d_in[0];
    const int*   ei  = (const int*)d_in[1];
    const float* W1  = (const float*)d_in[2];
    const float* b1  = (const float*)d_in[3];
    const float* g1  = (const float*)d_in[4];
    const float* be1 = (const float*)d_in[5];
    const float* W2  = (const float*)d_in[6];
    const float* b2  = (const float*)d_in[7];
    const float* g2  = (const float*)d_in[8];
    const float* be2 = (const float*)d_in[9];
    const float* W3  = (const float*)d_in[10];
    const float* b3  = (const float*)d_in[11];

    int n = in_sizes[0] / IN_F;
    int e = in_sizes[1] / 2;
    const int* src = ei;
    const int* dst = ei + e;

    float* wsf = (float*)d_ws;
    size_t NP = ((size_t)(n + 256) + 255) & ~(size_t)255;
    size_t EP = ((size_t)e + 255) & ~(size_t)255;
    size_t NB = (((size_t)n * HID) + 255) & ~(size_t)255;

    int*   degi   = (int*)wsf;
    float* dinv   = wsf + NP;
    int*   rowptr = (int*)(wsf + 2 * NP);
    int*   cursor = (int*)(wsf + 3 * NP);
    float* stats  = wsf + 4 * NP;          // 256
    float* scsh   = stats + 256;           // 256
    int*   part   = (int*)(scsh + 256);    // 1024
    int*   bhist  = part + 1024;           // 512
    int*   boff   = bhist + 512;           // 520
    int*   bcur   = boff + 520;            // 512
    int*   csr    = bcur + 512;
    float* A      = (float*)csr + EP;      // hs buffer [n,64]
    float* B      = A + NB;                // z  buffer [n,64]
    float* hs3    = B + NB;                // [n,4]
    uint2* pairs  = (uint2*)B;             // alias: B first written after fill2 reads

    int nb = (n + 255) / 256;
    int eb = (e + CHUNK - 1) / CHUNK;      // chunked edge blocks
    int sb = (n + 1023) / 1024;
    int nbkt = (n + 255) >> BSH;           // buckets

    k_init <<<nb, 256, 0, stream>>>(degi, stats, bhist, n);
    k_count<<<eb, 256, 0, stream>>>(dst, degi, bhist, e);
    k_scan1<<<sb, 256, 0, stream>>>(degi, part, n);
    k_scan2<<<1, 1024, 0, stream>>>(part, sb);
    k_scan3<<<sb, 256, 0, stream>>>(degi, part, rowptr, cursor, dinv, n, e);
    k_bscan<<<1, 512, 0, stream>>>(bhist, boff, bcur, nbkt, e);
    k_bin  <<<eb, 256, 0, stream>>>(src, dst, bcur, pairs, e);
    k_fill2<<<nbkt, 256, 0, stream>>>(pairs, boff, cursor, csr);

    // layer 1
    k_gemm1<<<nb, 256, 0, stream>>>(x, W1, dinv, A, n);
    k_agg64<<<1024, 256, 0, stream>>>(A, rowptr, csr, dinv, b1, B, stats, stats + 64, n);
    k_bnstats<<<1, 64, 0, stream>>>(stats, stats + 64, g1, be1, scsh, n);

    // layer 2
    k_gemm2<<<nb, 256, 0, stream>>>(B, W2, scsh, dinv, A, n);
    k_agg64<<<1024, 256, 0, stream>>>(A, rowptr, csr, dinv, b2, B, stats + 128, stats + 192, n);
    k_bnstats<<<1, 64, 0, stream>>>(stats + 128, stats + 192, g2, be2, scsh + 128, n);

    // layer 3
    k_gemm3<<<nb, 256, 0, stream>>>(B, W3, scsh + 128, dinv, hs3, n);
    k_agg4 <<<nb, 256, 0, stream>>>(hs3, rowptr, csr, dinv, b3, (float*)d_out, n);
}